// Round 7
// baseline (412.067 us; speedup 1.0000x reference)
//
#include <hip/hip_runtime.h>
#include <hip/hip_fp16.h>
#include <math.h>

#define NHEAD 8
#define NEG_SLOPE 0.2f
#define OUT_COLS 80

__device__ __forceinline__ float lrelu(float x) {
    return x > 0.f ? x : NEG_SLOPE * x;
}

__device__ __forceinline__ float f4elem(const float4& v, int kk) {
    return kk == 0 ? v.x : kk == 1 ? v.y : kk == 2 ? v.z : v.w;
}

// FMA one 16-float k-chunk (4 float4 per node) into acc tiles.
// Wbase = W + (size_t)chunk_k0 * HC + j0u.
template<int HC>
__device__ __forceinline__ void chunk_fma(
    const float4 (&X0)[4], const float4 (&X1)[4],
    const float* __restrict__ Wbase,
    float (&acc0)[32], float (&acc1)[32]) {
#pragma unroll
    for (int q4 = 0; q4 < 4; ++q4) {
#pragma unroll
        for (int kk = 0; kk < 4; ++kk) {
            const float xk0 = f4elem(X0[q4], kk);
            const float xk1 = f4elem(X1[q4], kk);
            const float4* __restrict__ W4 =
                (const float4*)(Wbase + (size_t)(q4 * 4 + kk) * HC);
#pragma unroll
            for (int q = 0; q < 8; ++q) {
                const float4 wq = W4[q];
                acc0[q * 4 + 0] += xk0 * wq.x;  acc1[q * 4 + 0] += xk1 * wq.x;
                acc0[q * 4 + 1] += xk0 * wq.y;  acc1[q * 4 + 1] += xk1 * wq.y;
                acc0[q * 4 + 2] += xk0 * wq.z;  acc1[q * 4 + 2] += xk1 * wq.z;
                acc0[q * 4 + 3] += xk0 * wq.w;  acc1[q * 4 + 3] += xk1 * wq.w;
            }
        }
    }
}

__device__ __forceinline__ void chunk_load(const float* __restrict__ p, float4 (&X)[4]) {
#pragma unroll
    for (int q = 0; q < 4; ++q) X[q] = *(const float4*)(p + q * 4);
}

// ---------------- projection: outer-product tile, 2 nodes per lane ----------------
// Block = 4 waves. Wave: 128 nodes (lane -> n, n+64) x 32 cols. xp stored fp16.
// x rows stream through a register double-buffer: prefetch chunk ch+1 while
// computing chunk ch -> HBM latency hidden under ~2048 cy of FMAs.
template<int HC, int C>
__device__ __forceinline__ void proj_epilogue(
    const float (&acc)[32], int n, int n_nodes, int j0, int j0u,
    const float* __restrict__ as_flat, const float* __restrict__ ad_flat,
    __half* __restrict__ xp, float* __restrict__ a_s, float* __restrict__ a_d) {
    float ps[2] = {0.f, 0.f}, pd[2] = {0.f, 0.f};
#pragma unroll
    for (int q = 0; q < 32; ++q) {
        const int g = (C == 16 && q >= 16) ? 1 : 0;
        ps[g] += acc[q] * as_flat[j0u + q];
        pd[g] += acc[q] * ad_flat[j0u + q];
    }
    if (n < n_nodes) {
        __half2 buf[16];
#pragma unroll
        for (int q = 0; q < 16; ++q)
            buf[q] = __float22half2_rn(make_float2(acc[2 * q], acc[2 * q + 1]));
        float4* dst = (float4*)(xp + (size_t)n * HC + j0);
        const float4* srcb = (const float4*)buf;
#pragma unroll
        for (int q = 0; q < 4; ++q) dst[q] = srcb[q];
        if (C == 32) {
            const int h = j0 / 32;
            a_s[(size_t)n * NHEAD + h] = ps[0];
            a_d[(size_t)n * NHEAD + h] = pd[0];
        } else {
            const int h = j0 / 16;
            a_s[(size_t)n * NHEAD + h] = ps[0];
            a_s[(size_t)n * NHEAD + h + 1] = ps[1];
            a_d[(size_t)n * NHEAD + h] = pd[0];
            a_d[(size_t)n * NHEAD + h + 1] = pd[1];
        }
    }
}

template<int DIN, int HC, int C>
__global__ __launch_bounds__(256) void proj_kernel(
    const float* __restrict__ xin, int xstride, int xoff,
    const float* __restrict__ W,
    const float* __restrict__ as_flat, const float* __restrict__ ad_flat,
    __half* __restrict__ xp, float* __restrict__ a_s, float* __restrict__ a_d,
    int n_nodes) {
    const int lane = threadIdx.x & 63;
    const int wv = threadIdx.x >> 6;
    const int j0 = blockIdx.x * 128 + wv * 32;
    const int j0u = __builtin_amdgcn_readfirstlane(j0);
    const int n0 = blockIdx.y * 128 + lane;
    const int nlast = n_nodes - 1;
    const int nc0 = min(n0, nlast);
    const int nc1 = min(n0 + 64, nlast);

    float acc0[32], acc1[32];
#pragma unroll
    for (int q = 0; q < 32; ++q) { acc0[q] = 0.f; acc1[q] = 0.f; }

    const float* __restrict__ xr0 = xin + (size_t)nc0 * xstride + xoff;
    const float* __restrict__ xr1 = xin + (size_t)nc1 * xstride + xoff;
    const float* __restrict__ Wj = W + j0u;

    constexpr int NCH = DIN / 16;    // 16-float chunks per row
    float4 A0[4], A1[4], B0[4], B1[4];
    chunk_load(xr0, A0);
    chunk_load(xr1, A1);

    if constexpr (NCH == 1) {
        chunk_fma<HC>(A0, A1, Wj, acc0, acc1);
    } else {
#pragma unroll 1
        for (int ch = 0; ch < NCH; ch += 2) {
            // prefetch chunk ch+1 (always exists: NCH even)
            chunk_load(xr0 + (ch + 1) * 16, B0);
            chunk_load(xr1 + (ch + 1) * 16, B1);
            chunk_fma<HC>(A0, A1, Wj + (size_t)(ch * 16) * HC, acc0, acc1);
            if (ch + 2 < NCH) {
                chunk_load(xr0 + (ch + 2) * 16, A0);
                chunk_load(xr1 + (ch + 2) * 16, A1);
            }
            chunk_fma<HC>(B0, B1, Wj + (size_t)((ch + 1) * 16) * HC, acc0, acc1);
        }
    }

    proj_epilogue<HC, C>(acc0, n0, n_nodes, j0, j0u, as_flat, ad_flat, xp, a_s, a_d);
    proj_epilogue<HC, C>(acc1, n0 + 64, n_nodes, j0, j0u, as_flat, ad_flat, xp, a_s, a_d);
}

// ---------------- CSR build ----------------
__global__ void hist_kernel(const int* __restrict__ ei, int E, int* __restrict__ deg) {
    const int e = blockIdx.x * blockDim.x + threadIdx.x;
    if (e < E) atomicAdd(&deg[ei[E + e]], 1);
}

__global__ __launch_bounds__(256) void blocksum_kernel(const int* __restrict__ deg, int N,
                                                       int* __restrict__ bsum) {
    __shared__ int red[256];
    const int t = threadIdx.x;
    const int base = blockIdx.x * 1024 + t * 4;
    int s = 0;
    if (base + 3 < N) {
        const int4 v = *(const int4*)(deg + base);
        s = v.x + v.y + v.z + v.w;
    } else {
#pragma unroll
        for (int i = 0; i < 4; ++i) if (base + i < N) s += deg[base + i];
    }
    red[t] = s;
    __syncthreads();
    for (int off = 128; off > 0; off >>= 1) {
        if (t < off) red[t] += red[t + off];
        __syncthreads();
    }
    if (t == 0) bsum[blockIdx.x] = red[0];
}

__global__ __launch_bounds__(64) void bscan_kernel(int* __restrict__ bsum, int NB) {
    const int lane = threadIdx.x;
    int run = 0;
    for (int base = 0; base < NB; base += 64) {
        const int i = base + lane;
        const int v = (i < NB) ? bsum[i] : 0;
        int inc = v;
#pragma unroll
        for (int off = 1; off < 64; off <<= 1) {
            const int u = __shfl_up(inc, off, 64);
            if (lane >= off) inc += u;
        }
        if (i < NB) bsum[i] = run + inc - v;
        run += __shfl(inc, 63, 64);
    }
}

__global__ __launch_bounds__(256) void rowptr_kernel(const int* __restrict__ deg,
                                                     const int* __restrict__ bsum,
                                                     int N, int E,
                                                     int* __restrict__ rowptr,
                                                     int* __restrict__ cursor) {
    __shared__ int tsum[256];
    const int t = threadIdx.x;
    const int base = blockIdx.x * 1024 + t * 4;
    int v[4];
    int s = 0;
#pragma unroll
    for (int i = 0; i < 4; ++i) {
        v[i] = (base + i < N) ? deg[base + i] : 0;
        s += v[i];
    }
    tsum[t] = s;
    __syncthreads();
    for (int off = 1; off < 256; off <<= 1) {
        const int u = (t >= off) ? tsum[t - off] : 0;
        __syncthreads();
        tsum[t] += u;
        __syncthreads();
    }
    int run = bsum[blockIdx.x] + tsum[t] - s;
#pragma unroll
    for (int i = 0; i < 4; ++i) {
        if (base + i < N) {
            rowptr[base + i] = run;
            cursor[base + i] = run;
            run += v[i];
        }
    }
    if (blockIdx.x == 0 && t == 0) rowptr[N] = E;
}

__global__ void scatter_kernel(const int* __restrict__ ei, int E,
                               int* __restrict__ cursor, int* __restrict__ csr_src) {
    const int e = blockIdx.x * blockDim.x + threadIdx.x;
    if (e < E) {
        const int pos = atomicAdd(&cursor[ei[E + e]], 1);
        csr_src[pos] = ei[e];
    }
}

// ---------------- fused softmax+aggregation: one wave per dst ----------------
// Items = deg edges + 1 self-loop. Phase A: lane=(slot,head) computes unnormalized ex.
// Phase B: LPE lanes fetch an edge's full fp16 row as 16B/lane; acc[8] fp32 per lane.
template<int C>
__global__ __launch_bounds__(256) void aggr_kernel(
    const int* __restrict__ rowptr, const int* __restrict__ csr_src,
    const float* __restrict__ a_s, const float* __restrict__ a_d,
    const __half* __restrict__ xp, const float* __restrict__ bias,
    float* __restrict__ out, int out_off, int N) {
    constexpr int HC = NHEAD * C;
    constexpr int LPE = HC / 8;     // lanes per edge-row (32 or 16)
    constexpr int EPW = 64 / LPE;   // edges in flight per wave (2 or 4)
    constexpr int CQ = C / 8;       // c-octs per head (4 or 2)
    const int n = (blockIdx.x * blockDim.x + threadIdx.x) >> 6;
    if (n >= N) return;
    const int lane = threadIdx.x & 63;
    const int iA = lane >> 3, hA = lane & 7;        // phase-A role
    const int le = lane & (LPE - 1);                // phase-B role
    const int epar = lane / LPE;
    const int h = le / CQ;
    const int c0 = (le % CQ) * 8;
    const int row0 = rowptr[n];
    const int deg = rowptr[n + 1] - row0;
    const int items = deg + 1;                      // + self-loop

    const float adhA = a_d[(size_t)n * NHEAD + hA];
    float sacc = 0.f;
    float acc[8];
#pragma unroll
    for (int j = 0; j < 8; ++j) acc[j] = 0.f;

    for (int base = 0; base < items; base += 8) {
        const int idx = base + iA;
        int src = n;
        float ex = 0.f;
        if (idx < items) {
            if (idx < deg) src = csr_src[row0 + idx];
            ex = expf(lrelu(a_s[(size_t)src * NHEAD + hA] + adhA));
        }
        sacc += ex;
        const int cnt = min(items - base, 8);
        for (int g = 0; g < cnt; g += EPW) {
            const int it = g + epar;
            const int srcb = __shfl(src, it * 8, 64);
            const float exb = __shfl(ex, it * 8 + h, 64);
            if (it < cnt) {
                const float4 r = *(const float4*)(xp + (size_t)srcb * HC + h * C + c0);
                const __half2* h2 = (const __half2*)&r;
#pragma unroll
                for (int q = 0; q < 4; ++q) {
                    const float2 f = __half22float2(h2[q]);
                    acc[2 * q]     += exb * f.x;
                    acc[2 * q + 1] += exb * f.y;
                }
            }
        }
    }
    // softmax denominators: reduce over slots -> lane L holds s for head L&7
    sacc += __shfl_xor(sacc, 8, 64);
    sacc += __shfl_xor(sacc, 16, 64);
    sacc += __shfl_xor(sacc, 32, 64);
    const float sinv = 1.f / __shfl(sacc, h, 64);

    // combine edge-parallel copies (same (h,c-oct), different edge subsets)
#pragma unroll
    for (int off = LPE; off < 64; off <<= 1) {
#pragma unroll
        for (int j = 0; j < 8; ++j) acc[j] += __shfl_xor(acc[j], off, 64);
    }
#pragma unroll
    for (int j = 0; j < 8; ++j) acc[j] *= sinv;      // per-head normalize
    // head-mean reduce (over h lanes)
#pragma unroll
    for (int off = CQ; off < LPE; off <<= 1) {
#pragma unroll
        for (int j = 0; j < 8; ++j) acc[j] += __shfl_xor(acc[j], off, 64);
    }
    if (lane < CQ) {
        float v[8];
#pragma unroll
        for (int j = 0; j < 8; ++j)
            v[j] = fmaxf(acc[j] * (1.f / NHEAD) + bias[lane * 8 + j], 0.f);
        float* op = out + (size_t)n * OUT_COLS + out_off + lane * 8;
        *(float4*)op = make_float4(v[0], v[1], v[2], v[3]);
        *(float4*)(op + 4) = make_float4(v[4], v[5], v[6], v[7]);
    }
}

static inline size_t align_up(size_t x) { return (x + 255) & ~size_t(255); }

extern "C" void kernel_launch(void* const* d_in, const int* in_sizes, int n_in,
                              void* d_out, int out_size, void* d_ws, size_t ws_size,
                              hipStream_t stream) {
    const float* x  = (const float*)d_in[0];
    const int*   ei = (const int*)d_in[1];
    const float* W1  = (const float*)d_in[2];
    const float* as1 = (const float*)d_in[3];
    const float* ad1 = (const float*)d_in[4];
    const float* b1  = (const float*)d_in[5];
    const float* W2  = (const float*)d_in[6];
    const float* as2 = (const float*)d_in[7];
    const float* ad2 = (const float*)d_in[8];
    const float* b2  = (const float*)d_in[9];
    const float* W3  = (const float*)d_in[10];
    const float* as3 = (const float*)d_in[11];
    const float* ad3 = (const float*)d_in[12];
    const float* b3  = (const float*)d_in[13];
    float* out = (float*)d_out;

    const int N = in_sizes[0] / 128;
    const int E = in_sizes[1] / 2;

    // workspace layout
    char* w = (char*)d_ws;
    __half* xp    = (__half*)w; w += align_up((size_t)N * 256 * 2);
    float* a_s    = (float*)w;  w += align_up((size_t)N * NHEAD * 4);
    float* a_d    = (float*)w;  w += align_up((size_t)N * NHEAD * 4);
    int*   deg    = (int*)w;    w += align_up((size_t)N * 4);
    int*   rowptr = (int*)w;    w += align_up((size_t)(N + 1) * 4);
    int*   cursor = (int*)w;    w += align_up((size_t)N * 4);
    int*   csrsrc = (int*)w;    w += align_up((size_t)E * 4);
    int*   bsum   = (int*)w;    w += align_up(((size_t)N / 1024 + 2) * 4);

    const int EB = 256;
    const int eg = (E + EB - 1) / EB;
    const int ntiles = (N + 127) / 128;     // 128 nodes per block (2 per lane)
    const int ngrid = (N + 3) / 4;          // 4 dst-waves per 256-thread block
    const int NB = (N + 1023) / 1024;       // scan chunks

    // ---- CSR build (once, reused by all 3 layers) ----
    hipMemsetAsync(deg, 0, (size_t)N * 4, stream);
    hist_kernel<<<eg, EB, 0, stream>>>(ei, E, deg);
    blocksum_kernel<<<NB, 256, 0, stream>>>(deg, N, bsum);
    bscan_kernel<<<1, 64, 0, stream>>>(bsum, NB);
    rowptr_kernel<<<NB, 256, 0, stream>>>(deg, bsum, N, E, rowptr, cursor);
    scatter_kernel<<<eg, EB, 0, stream>>>(ei, E, cursor, csrsrc);

    // ---------------- Layer 1: din=128, C=32, HC=256 ----------------
    proj_kernel<128, 256, 32><<<dim3(2, ntiles), 256, 0, stream>>>(
        x, 128, 0, W1, as1, ad1, xp, a_s, a_d, N);
    aggr_kernel<32><<<ngrid, 256, 0, stream>>>(rowptr, csrsrc, a_s, a_d, xp, b1, out, 0, N);

    // ---------------- Layer 2: din=32, C=16, HC=128 (input = out[:,0:32]) ----------------
    proj_kernel<32, 128, 16><<<dim3(1, ntiles), 256, 0, stream>>>(
        out, OUT_COLS, 0, W2, as2, ad2, xp, a_s, a_d, N);
    aggr_kernel<16><<<ngrid, 256, 0, stream>>>(rowptr, csrsrc, a_s, a_d, xp, b2, out, 32, N);

    // ---------------- Layer 3: din=16, C=32, HC=256 (input = out[:,32:48]) ----------------
    proj_kernel<16, 256, 32><<<dim3(2, ntiles), 256, 0, stream>>>(
        out, OUT_COLS, 32, W3, as3, ad3, xp, a_s, a_d, N);
    aggr_kernel<32><<<ngrid, 256, 0, stream>>>(rowptr, csrsrc, a_s, a_d, xp, b3, out, 48, N);
}